// Round 17
// baseline (165.133 us; speedup 1.0000x reference)
//
#include <hip/hip_runtime.h>
#include <hip/hip_bf16.h>
#include <math.h>

// Problem constants
#define T_ 4
#define N_ 16
#define F_ 6
#define L_ 1024
#define A_ 21
#define K_ 20
#define U_ 256
#define LOUT 1005            // L - K + 1
#define NIMG 384             // T*N*F
#define SZ_S (T_*N_*U_)      // 16384
#define SZ_R (K_*A_*U_)      // 107520

// Packed-X geometry: row stride 24 shorts (48 B). For output row l, contraction
// slot c maps to tap=c/24, col=c%24 (independent of l). Valid slots 0..476 ->
// 15 K-steps of 32 (480); cols 21..23 zero in R.
#define XPR 24               // shorts per packed row
#define XROWS 1056           // padded rows per image
#define NSTEP 15             // K-steps of 32 slots
#define XCH 26               // X LDS chunks of 1 KB (554 rows >= 531 needed)

typedef __attribute__((ext_vector_type(8))) short short8;   // 8 bf16 (4 VGPR)
typedef __attribute__((ext_vector_type(4))) float f32x4;    // 4 f32 acc

__device__ __forceinline__ unsigned short f2bf(float f) {
  unsigned int u = __float_as_uint(f);
  u += 0x7FFFu + ((u >> 16) & 1u);   // round to nearest even
  return (unsigned short)(u >> 16);
}

__device__ __forceinline__ void atomicMaxF(float* addr, float val) {
  if (val >= 0.f) atomicMax((int*)addr, __float_as_int(val));
  else            atomicMin((unsigned int*)addr, __float_as_uint(val));
}

// Async global->LDS, 16B per lane. LDS dest is wave-uniform base + lane*16.
__device__ __forceinline__ void gload_lds16(const void* g, void* l) {
  __builtin_amdgcn_global_load_lds(
      (const __attribute__((address_space(1))) void*)g,
      (__attribute__((address_space(3))) void*)l, 16, 0, 0);
}

// Merged pre-pass (single launch): S init, R (fp32 exact) -> d_out,
// Rt = bf16 R in slot order Rt[(s>>5)*(U*32) + u*32 + (s&31)] (pads zeroed),
// X fp32 -> packed bf16 Xp.
__global__ void xprep_kernel(const float* __restrict__ X,
                             const float* __restrict__ P_logit,
                             const float* __restrict__ Q,
                             float* __restrict__ out,
                             unsigned short* __restrict__ Rt,
                             unsigned int* __restrict__ Xp32) {
  int t = blockIdx.x * blockDim.x + threadIdx.x;
  if (t < SZ_S) out[t] = -INFINITY;            // S init for atomic max

  if (t < K_ * U_) {                           // R / Rt part
    int k = t / U_;
    int u = t - k * U_;
    const float* pl = P_logit + (size_t)k * A_ * U_ + u;
    float v[A_];
    float m = -INFINITY;
#pragma unroll
    for (int a = 0; a < A_; ++a) { v[a] = pl[(size_t)a * U_]; m = fmaxf(m, v[a]); }
    float s = 0.f;
#pragma unroll
    for (int a = 0; a < A_; ++a) { v[a] = expf(v[a] - m); s += v[a]; }
    float qs = 0.f;
#pragma unroll
    for (int a = 0; a < A_; ++a) qs += Q[a];
    float eps = qs * (1.0f / A_);
    float invs = 1.f / s;
    float* Rout = out + SZ_S;
#pragma unroll
    for (int a = 0; a < XPR; ++a) {
      unsigned short bv = 0;
      if (a < A_) {
        float r = logf(fmaxf(v[a] * invs / Q[a], eps));
        Rout[(size_t)(k * A_ + a) * U_ + u] = r;
        bv = f2bf(r);
      }
      int sl = k * XPR + a;
      Rt[(size_t)(sl >> 5) * (U_ * 32) + u * 32 + (sl & 31)] = bv;
    }
  }

  if (t < NIMG * XROWS * 12) {                 // X conversion part
    int w  = t % 12;
    int rl = t / 12;               // n*XROWS + row
    int row = rl % XROWS;
    int n   = rl / XROWS;
    int c0 = w * 2;
    float v0 = 0.f, v1 = 0.f;
    if (row < L_) {
      const float* xr = X + ((size_t)n * L_ + row) * A_;
      if (c0 < A_)     v0 = xr[c0];
      if (c0 + 1 < A_) v1 = xr[c0 + 1];
    }
    unsigned int o = (unsigned int)f2bf(v0) | ((unsigned int)f2bf(v1) << 16);
    Xp32[(size_t)rl * 12 + w] = o;
  }
}

// Conv as one GEMM: M=u (A=R slots), N=l (B=packed-X window), K=480 (15 steps).
// R17 = R16 persistent-R structure at 2 waves/SIMD: 512 threads, 8 waves
// (2u x 4l), wave tile 64u x 128l unchanged (12 ds_read / 32 MFMA per step),
// block covers 128u x 512l -> 2 l-tiles per image. R (120 KB) staged once;
// X = ONE 26 KB buffer, restaged once mid-block: [K-loop t0] -> barrier ->
// stage X(t1) -> stores(t0) -> vmcnt(32) (stage loads are oldest -> certified;
// stores stay in flight, draining under K-loop t1) -> barrier -> [K-loop t1].
// K-loops remain pure {ds_read + MFMA} with zero sync; the second wave per
// SIMD overlaps one wave's LDS waits with the other's MFMA issue (m114).
__global__ __launch_bounds__(512, 2) void conv_kernel(
    const unsigned short* __restrict__ Xp,
    const unsigned short* __restrict__ Rt,
    float* __restrict__ out) {
  __shared__ __align__(16) unsigned short lds_r[NSTEP * 4096];   // 120 KB
  __shared__ __align__(16) unsigned short lds_x[XCH * 512];      // 26 KB

  const int n  = blockIdx.z;
  const int u0 = blockIdx.x * 128;
  const int wid  = threadIdx.x >> 6;   // 0..7
  const int lane = threadIdx.x & 63;
  const int wl = wid >> 1;             // wave l position (0..3), 128 l each
  const int wu = wid & 1;              // wave u position (0..1), 64 u each

  const char* xsrc = (const char*)Xp + (size_t)n * XROWS * (XPR * 2);
  const char* rsrc = (const char*)Rt + (size_t)u0 * 64;   // block's u-half

  // ---- prologue: ALL of R (15 chunks/wave) + X tile 0 (3-4 chunks/wave)
  for (int c = wid; c < NSTEP * 8; c += 8)
    gload_lds16(rsrc + (size_t)(c >> 3) * (U_ * 64) + (c & 7) * 1024 + lane * 16,
                (char*)lds_r + c * 1024);
  for (int c = wid; c < XCH; c += 8)
    gload_lds16(xsrc + c * 1024 + lane * 16, (char*)lds_x + c * 1024);
  asm volatile("s_waitcnt vmcnt(0)" ::: "memory");
  __builtin_amdgcn_s_barrier();

  const int fl = lane & 15;            // frag row (A: u) / col (B: l)
  const int fj = lane >> 4;            // k sub-chunk (8 shorts each)
  // R frag(kk, ut): lds_r + kk*4096 + (wu*64 + ut*16 + fl)*32 + fj*8
  const int rfo = (wu * 64 + fl) * 32 + (fj << 3);
  const int xro = (wl * 128 + fl) * XPR + (fj << 3);
  const int ug = fj << 2;

  float* Z = out + SZ_S + SZ_R;
  float pmax[4][4];                    // [ut][reg], carried across both tiles
#pragma unroll
  for (int ut = 0; ut < 4; ++ut)
#pragma unroll
    for (int r = 0; r < 4; ++r) pmax[ut][r] = -INFINITY;

#pragma unroll 1
  for (int t = 0; t < 2; ++t) {
    f32x4 acc[4][8];                   // [ut][lt]
#pragma unroll
    for (int ut = 0; ut < 4; ++ut)
#pragma unroll
      for (int lt = 0; lt < 8; ++lt)
        acc[ut][lt] = (f32x4){0.f, 0.f, 0.f, 0.f};

    // ---- K-loop: no sync of any kind; compiler software-pipelines, and the
    // second wave on each SIMD fills LDS-wait bubbles with its MFMAs.
    const unsigned short* xb = lds_x + xro;
#pragma unroll
    for (int k = 0; k < NSTEP; ++k) {
      short8 xfr[8], rfr[4];
      const unsigned short* rb = lds_r + k * 4096 + rfo;
#pragma unroll
      for (int lt = 0; lt < 8; ++lt)
        xfr[lt] = *(const short8*)(xb + lt * (16 * XPR) + k * 32);
#pragma unroll
      for (int ut = 0; ut < 4; ++ut)
        rfr[ut] = *(const short8*)(rb + ut * (16 * 32));
#pragma unroll
      for (int ut = 0; ut < 4; ++ut)
#pragma unroll
        for (int lt = 0; lt < 8; ++lt)
          acc[ut][lt] = __builtin_amdgcn_mfma_f32_16x16x32_bf16(
              rfr[ut], xfr[lt], acc[ut][lt], 0, 0, 0);
    }

    if (t == 0) {
      // all waves done reading lds_x tile 0 before the overwrite
      __builtin_amdgcn_s_barrier();
      // stage X tile 1 (rows 512..1065; 531 needed, over-read harmless)
      const char* xs = xsrc + (size_t)512 * (XPR * 2);
      for (int c = wid; c < XCH; c += 8)
        gload_lds16(xs + c * 1024 + lane * 16, (char*)lds_x + c * 1024);
    }

    // ---- Z stores (issued after the stage so stage loads are OLDEST;
    // fire-and-forget, drain under tile 1's K-loop / next block's prologue)
#pragma unroll
    for (int lt = 0; lt < 8; ++lt) {
      const int l = t * 512 + wl * 128 + lt * 16 + fl;
      if (l < LOUT) {
        float* zrow = Z + ((size_t)n * LOUT + l) * U_ + u0 + wu * 64 + ug;
#pragma unroll
        for (int ut = 0; ut < 4; ++ut) {
          f32x4 v = acc[ut][lt];
          *(f32x4*)(zrow + ut * 16) = v;
#pragma unroll
          for (int r = 0; r < 4; ++r) pmax[ut][r] = fmaxf(pmax[ut][r], v[r]);
        }
      }
    }

    if (t == 0) {
      // certify the stage (outstanding = stage(3-4) + 32 stores; waiting to
      // <=32 retires the OLDEST 3-4 = the stage loads; stores stay in flight)
      asm volatile("s_waitcnt vmcnt(32)" ::: "memory");
      __builtin_amdgcn_s_barrier();
    }
  }

  // ---- S epilogue: reduce over the frag's 16 cols (fl), atomics once.
#pragma unroll
  for (int off = 1; off < 16; off <<= 1)
#pragma unroll
    for (int ut = 0; ut < 4; ++ut)
#pragma unroll
      for (int r = 0; r < 4; ++r)
        pmax[ut][r] = fmaxf(pmax[ut][r], __shfl_xor(pmax[ut][r], off));

  if (fl == 0) {                       // lanes fj*16
    const int tn = n / F_;
    float* Sp = out + (size_t)tn * U_ + u0 + wu * 64 + ug;
#pragma unroll
    for (int ut = 0; ut < 4; ++ut)
#pragma unroll
      for (int r = 0; r < 4; ++r)
        atomicMaxF(Sp + ut * 16 + r, pmax[ut][r]);
  }
}

extern "C" void kernel_launch(void* const* d_in, const int* in_sizes, int n_in,
                              void* d_out, int out_size, void* d_ws, size_t ws_size,
                              hipStream_t stream) {
  const float* X       = (const float*)d_in[0];
  const float* P_logit = (const float*)d_in[1];
  const float* Q       = (const float*)d_in[2];
  float* out = (float*)d_out;

  unsigned short* Rt = (unsigned short*)d_ws;            // 240 KB
  unsigned short* Xp = (unsigned short*)((char*)d_ws + 262144);
  // Xp: NIMG*XROWS*24 shorts (~18.6 MB). Last image's tile-1 stage over-reads
  // ~0.5 KB past Xp into ws slack (poison = finite bf16; affected rows feed
  // only l >= LOUT outputs, which are guarded and never stored).

  int xthreads = NIMG * XROWS * 12;
  hipLaunchKernelGGL(xprep_kernel, dim3((xthreads + 255) / 256), dim3(256),
                     0, stream, X, P_logit, Q, out, Rt, (unsigned int*)Xp);
  dim3 grid(2, 1, NIMG);   // u-tiles, -, images (2 l-tiles looped in-kernel)
  hipLaunchKernelGGL(conv_kernel, grid, dim3(512), 0, stream, Xp, Rt, out);
}

// Round 18
// 140.615 us; speedup vs baseline: 1.1744x; 1.1744x over previous
//
#include <hip/hip_runtime.h>
#include <hip/hip_bf16.h>
#include <math.h>

// Problem constants
#define T_ 4
#define N_ 16
#define F_ 6
#define L_ 1024
#define A_ 21
#define K_ 20
#define U_ 256
#define LOUT 1005            // L - K + 1
#define NIMG 384             // T*N*F
#define SZ_S (T_*N_*U_)      // 16384
#define SZ_R (K_*A_*U_)      // 107520

// Packed-X geometry: row stride 24 shorts (48 B). For output row l, contraction
// slot c maps to tap=c/24, col=c%24 (independent of l). Valid slots 0..476 ->
// 15 K-steps of 32 (480); cols 21..23 zero in R.
#define XPR 24               // shorts per packed row
#define XROWS 1056           // padded rows per image
#define NSTEP 15             // K-steps of 32 slots
#define XWCH 7               // private X chunks of 1 KB per wave (149 rows)

typedef __attribute__((ext_vector_type(8))) short short8;   // 8 bf16 (4 VGPR)
typedef __attribute__((ext_vector_type(4))) float f32x4;    // 4 f32 acc

__device__ __forceinline__ unsigned short f2bf(float f) {
  unsigned int u = __float_as_uint(f);
  u += 0x7FFFu + ((u >> 16) & 1u);   // round to nearest even
  return (unsigned short)(u >> 16);
}

__device__ __forceinline__ void atomicMaxF(float* addr, float val) {
  if (val >= 0.f) atomicMax((int*)addr, __float_as_int(val));
  else            atomicMin((unsigned int*)addr, __float_as_uint(val));
}

// Async global->LDS, 16B per lane. LDS dest is wave-uniform base + lane*16.
__device__ __forceinline__ void gload_lds16(const void* g, void* l) {
  __builtin_amdgcn_global_load_lds(
      (const __attribute__((address_space(1))) void*)g,
      (__attribute__((address_space(3))) void*)l, 16, 0, 0);
}

// Merged pre-pass (single launch): S init, R (fp32 exact) -> d_out,
// Rt = bf16 R in slot order Rt[(s>>5)*(U*32) + u*32 + (s&31)] (pads zeroed),
// X fp32 -> packed bf16 Xp.
__global__ void xprep_kernel(const float* __restrict__ X,
                             const float* __restrict__ P_logit,
                             const float* __restrict__ Q,
                             float* __restrict__ out,
                             unsigned short* __restrict__ Rt,
                             unsigned int* __restrict__ Xp32) {
  int t = blockIdx.x * blockDim.x + threadIdx.x;
  if (t < SZ_S) out[t] = -INFINITY;            // S init for atomic max

  if (t < K_ * U_) {                           // R / Rt part
    int k = t / U_;
    int u = t - k * U_;
    const float* pl = P_logit + (size_t)k * A_ * U_ + u;
    float v[A_];
    float m = -INFINITY;
#pragma unroll
    for (int a = 0; a < A_; ++a) { v[a] = pl[(size_t)a * U_]; m = fmaxf(m, v[a]); }
    float s = 0.f;
#pragma unroll
    for (int a = 0; a < A_; ++a) { v[a] = expf(v[a] - m); s += v[a]; }
    float qs = 0.f;
#pragma unroll
    for (int a = 0; a < A_; ++a) qs += Q[a];
    float eps = qs * (1.0f / A_);
    float invs = 1.f / s;
    float* Rout = out + SZ_S;
#pragma unroll
    for (int a = 0; a < XPR; ++a) {
      unsigned short bv = 0;
      if (a < A_) {
        float r = logf(fmaxf(v[a] * invs / Q[a], eps));
        Rout[(size_t)(k * A_ + a) * U_ + u] = r;
        bv = f2bf(r);
      }
      int sl = k * XPR + a;
      Rt[(size_t)(sl >> 5) * (U_ * 32) + u * 32 + (sl & 31)] = bv;
    }
  }

  if (t < NIMG * XROWS * 12) {                 // X conversion part
    int w  = t % 12;
    int rl = t / 12;               // n*XROWS + row
    int row = rl % XROWS;
    int n   = rl / XROWS;
    int c0 = w * 2;
    float v0 = 0.f, v1 = 0.f;
    if (row < L_) {
      const float* xr = X + ((size_t)n * L_ + row) * A_;
      if (c0 < A_)     v0 = xr[c0];
      if (c0 + 1 < A_) v1 = xr[c0 + 1];
    }
    unsigned int o = (unsigned int)f2bf(v0) | ((unsigned int)f2bf(v1) << 16);
    Xp32[(size_t)rl * 12 + w] = o;
  }
}

// Conv as one GEMM: M=u (A=R slots), N=l (B=packed-X window), K=480 (15 steps).
// R18 = R16 persistent-R with WAVE-PRIVATE X staging and ZERO barriers after
// the prologue. Each wave stages its own 147-row X window (7 KB incl. halo)
// into its own single buffer; tile t: [vmcnt(32) certifies own stage (issued
// one full tile ago)] -> pure K-loop -> stage(t+1) into own buffer (own reads
// already consumed) -> 32 Z stores fire-and-forget. Waves drift out of phase,
// so store bursts drain under other waves' MFMA phases; each wave's stores
// get a full K-loop before its next vmcnt touches them (max outstanding ~51
// < 63 cap). lds_r (120 KB) read-only after the single prologue barrier.
// 4 waves (2u x 2l), wave 64u x 128l (4x8 frags), 4 l-tiles of 256.
__global__ __launch_bounds__(256, 1) void conv_kernel(
    const unsigned short* __restrict__ Xp,
    const unsigned short* __restrict__ Rt,
    float* __restrict__ out) {
  __shared__ __align__(16) unsigned short lds_r[NSTEP * 4096];     // 120 KB
  __shared__ __align__(16) unsigned short lds_xp[4][XWCH * 512];   // 28 KB

  const int n  = blockIdx.z;
  const int u0 = blockIdx.x * 128;
  const int wid  = threadIdx.x >> 6;
  const int lane = threadIdx.x & 63;
  const int wl = wid >> 1;             // wave l position (0..1), 128 l each
  const int wu = wid & 1;              // wave u position (0..1), 64 u each

  // wave's private X source: rows t*256 + wl*128 .. +149 (halo 19 incl.)
  const char* xsrc = (const char*)Xp +
      ((size_t)n * XROWS + wl * 128) * (XPR * 2);
  const char* rsrc = (const char*)Rt + (size_t)u0 * 64;   // block's u-half
  char* xdst = (char*)&lds_xp[wid][0];

#define XSTAGE(T)                                                            \
  {                                                                          \
    const char* xs = xsrc + (size_t)(T) * (256 * XPR * 2);                   \
    _Pragma("unroll")                                                        \
    for (int c = 0; c < XWCH; ++c)                                           \
      gload_lds16(xs + c * 1024 + lane * 16, xdst + c * 1024);               \
  }

  // ---- prologue: ALL of R (30 chunks/wave, shared) + private X tile 0
  for (int c = wid; c < NSTEP * 8; c += 4)
    gload_lds16(rsrc + (size_t)(c >> 3) * (U_ * 64) + (c & 7) * 1024 + lane * 16,
                (char*)lds_r + c * 1024);
  XSTAGE(0)
  asm volatile("s_waitcnt vmcnt(0)" ::: "memory");
  __builtin_amdgcn_s_barrier();        // the ONLY barrier: lds_r visibility

  const int fl = lane & 15;            // frag row (A: u) / col (B: l)
  const int fj = lane >> 4;            // k sub-chunk (8 shorts each)
  // R frag(kk, ut): lds_r + kk*4096 + (wu*64 + ut*16 + fl)*32 + fj*8
  const int rfo = (wu * 64 + fl) * 32 + (fj << 3);
  // X frag(kk, lt): private buffer, row lt*16 + fl, shorts row*24 + kk*32 + fj*8
  const unsigned short* xb =
      (const unsigned short*)xdst + fl * XPR + (fj << 3);
  const int ug = fj << 2;

  float* Z = out + SZ_S + SZ_R;
  float pmax[4][4];                    // [ut][reg], carried across all tiles
#pragma unroll
  for (int ut = 0; ut < 4; ++ut)
#pragma unroll
    for (int r = 0; r < 4; ++r) pmax[ut][r] = -INFINITY;

#pragma unroll 1
  for (int t = 0; t < 4; ++t) {
    // head: certify own X stage (issued one full tile ago; for t=0 the
    // prologue's vmcnt(0) already certified). Own stores from tile t-2 are
    // long retired; tile t-1's 32 stores stay in flight (oldest-first).
    if (t > 0) asm volatile("s_waitcnt vmcnt(32)" ::: "memory");

    f32x4 acc[4][8];                   // [ut][lt]
#pragma unroll
    for (int ut = 0; ut < 4; ++ut)
#pragma unroll
      for (int lt = 0; lt < 8; ++lt)
        acc[ut][lt] = (f32x4){0.f, 0.f, 0.f, 0.f};

    // ---- K-loop: pure {ds_read + MFMA}, no sync; compiler pipelines.
#pragma unroll
    for (int k = 0; k < NSTEP; ++k) {
      short8 xfr[8], rfr[4];
      const unsigned short* rb = lds_r + k * 4096 + rfo;
#pragma unroll
      for (int lt = 0; lt < 8; ++lt)
        xfr[lt] = *(const short8*)(xb + lt * (16 * XPR) + k * 32);
#pragma unroll
      for (int ut = 0; ut < 4; ++ut)
        rfr[ut] = *(const short8*)(rb + ut * (16 * 32));
#pragma unroll
      for (int ut = 0; ut < 4; ++ut)
#pragma unroll
        for (int lt = 0; lt < 8; ++lt)
          acc[ut][lt] = __builtin_amdgcn_mfma_f32_16x16x32_bf16(
              rfr[ut], xfr[lt], acc[ut][lt], 0, 0, 0);
    }

    // ---- stage own X for tile t+1 (own reads above already consumed; no
    // other wave touches this buffer -> no barrier needed)
    if (t < 3) XSTAGE(t + 1)

    // ---- Z stores (fire-and-forget; drain during next tile's K-loop)
#pragma unroll
    for (int lt = 0; lt < 8; ++lt) {
      const int l = t * 256 + wl * 128 + lt * 16 + fl;
      if (l < LOUT) {
        float* zrow = Z + ((size_t)n * LOUT + l) * U_ + u0 + wu * 64 + ug;
#pragma unroll
        for (int ut = 0; ut < 4; ++ut) {
          f32x4 v = acc[ut][lt];
          *(f32x4*)(zrow + ut * 16) = v;
#pragma unroll
          for (int r = 0; r < 4; ++r) pmax[ut][r] = fmaxf(pmax[ut][r], v[r]);
        }
      }
    }
  }

#undef XSTAGE

  // ---- S epilogue: reduce over the frag's 16 cols (fl), atomics once.
#pragma unroll
  for (int off = 1; off < 16; off <<= 1)
#pragma unroll
    for (int ut = 0; ut < 4; ++ut)
#pragma unroll
      for (int r = 0; r < 4; ++r)
        pmax[ut][r] = fmaxf(pmax[ut][r], __shfl_xor(pmax[ut][r], off));

  if (fl == 0) {                       // lanes fj*16
    const int tn = n / F_;
    float* Sp = out + (size_t)tn * U_ + u0 + wu * 64 + ug;
#pragma unroll
    for (int ut = 0; ut < 4; ++ut)
#pragma unroll
      for (int r = 0; r < 4; ++r)
        atomicMaxF(Sp + ut * 16 + r, pmax[ut][r]);
  }
}

extern "C" void kernel_launch(void* const* d_in, const int* in_sizes, int n_in,
                              void* d_out, int out_size, void* d_ws, size_t ws_size,
                              hipStream_t stream) {
  const float* X       = (const float*)d_in[0];
  const float* P_logit = (const float*)d_in[1];
  const float* Q       = (const float*)d_in[2];
  float* out = (float*)d_out;

  unsigned short* Rt = (unsigned short*)d_ws;            // 240 KB
  unsigned short* Xp = (unsigned short*)((char*)d_ws + 262144);
  // Xp: NIMG*XROWS*24 shorts (~18.6 MB). Last image's tile-3 halo stage reads
  // rows <= 1043 < 1056 -- fully in-bounds; no over-read.

  int xthreads = NIMG * XROWS * 12;
  hipLaunchKernelGGL(xprep_kernel, dim3((xthreads + 255) / 256), dim3(256),
                     0, stream, X, P_logit, Q, out, Rt, (unsigned int*)Xp);
  dim3 grid(2, 1, NIMG);   // u-tiles, -, images (4 l-tiles looped in-kernel)
  hipLaunchKernelGGL(conv_kernel, grid, dim3(256), 0, stream, Xp, Rt, out);
}

// Round 19
// 130.925 us; speedup vs baseline: 1.2613x; 1.0740x over previous
//
#include <hip/hip_runtime.h>
#include <hip/hip_bf16.h>
#include <math.h>

// Problem constants
#define T_ 4
#define N_ 16
#define F_ 6
#define L_ 1024
#define A_ 21
#define K_ 20
#define U_ 256
#define LOUT 1005            // L - K + 1
#define NIMG 384             // T*N*F
#define SZ_S (T_*N_*U_)      // 16384
#define SZ_R (K_*A_*U_)      // 107520

// Packed-X geometry: row stride 24 shorts (48 B). For output row l, contraction
// slot c maps to tap=c/24, col=c%24 (independent of l). Valid slots 0..476 ->
// 15 K-steps of 32 (480); cols 21..23 zero in R.
#define XPR 24               // shorts per packed row
#define XROWS 1056           // padded rows per image
#define NSTEP 15             // K-steps of 32 slots
#define XWCH 7               // private X chunks of 1 KB per wave (149 rows)

typedef __attribute__((ext_vector_type(8))) short short8;   // 8 bf16 (4 VGPR)
typedef __attribute__((ext_vector_type(4))) float f32x4;    // 4 f32 acc
typedef __attribute__((ext_vector_type(4))) unsigned int uint4v;

__device__ __forceinline__ unsigned short f2bf(float f) {
  unsigned int u = __float_as_uint(f);
  u += 0x7FFFu + ((u >> 16) & 1u);   // round to nearest even
  return (unsigned short)(u >> 16);
}

__device__ __forceinline__ void atomicMaxF(float* addr, float val) {
  if (val >= 0.f) atomicMax((int*)addr, __float_as_int(val));
  else            atomicMin((unsigned int*)addr, __float_as_uint(val));
}

// Async global->LDS, 16B per lane. LDS dest is wave-uniform base + lane*16.
__device__ __forceinline__ void gload_lds16(const void* g, void* l) {
  __builtin_amdgcn_global_load_lds(
      (const __attribute__((address_space(1))) void*)g,
      (__attribute__((address_space(3))) void*)l, 16, 0, 0);
}

// Merged pre-pass (single launch): S init, R (fp32 exact) -> d_out,
// Rt = bf16 R in slot order Rt[(s>>5)*(U*32) + u*32 + (s&31)] (pads zeroed),
// X fp32 -> packed bf16 Xp.
__global__ void xprep_kernel(const float* __restrict__ X,
                             const float* __restrict__ P_logit,
                             const float* __restrict__ Q,
                             float* __restrict__ out,
                             unsigned short* __restrict__ Rt,
                             unsigned int* __restrict__ Xp32) {
  int t = blockIdx.x * blockDim.x + threadIdx.x;
  if (t < SZ_S) out[t] = -INFINITY;            // S init for atomic max

  if (t < K_ * U_) {                           // R / Rt part
    int k = t / U_;
    int u = t - k * U_;
    const float* pl = P_logit + (size_t)k * A_ * U_ + u;
    float v[A_];
    float m = -INFINITY;
#pragma unroll
    for (int a = 0; a < A_; ++a) { v[a] = pl[(size_t)a * U_]; m = fmaxf(m, v[a]); }
    float s = 0.f;
#pragma unroll
    for (int a = 0; a < A_; ++a) { v[a] = expf(v[a] - m); s += v[a]; }
    float qs = 0.f;
#pragma unroll
    for (int a = 0; a < A_; ++a) qs += Q[a];
    float eps = qs * (1.0f / A_);
    float invs = 1.f / s;
    float* Rout = out + SZ_S;
#pragma unroll
    for (int a = 0; a < XPR; ++a) {
      unsigned short bv = 0;
      if (a < A_) {
        float r = logf(fmaxf(v[a] * invs / Q[a], eps));
        Rout[(size_t)(k * A_ + a) * U_ + u] = r;
        bv = f2bf(r);
      }
      int sl = k * XPR + a;
      Rt[(size_t)(sl >> 5) * (U_ * 32) + u * 32 + (sl & 31)] = bv;
    }
  }

  if (t < NIMG * XROWS * 12) {                 // X conversion part
    int w  = t % 12;
    int rl = t / 12;               // n*XROWS + row
    int row = rl % XROWS;
    int n   = rl / XROWS;
    int c0 = w * 2;
    float v0 = 0.f, v1 = 0.f;
    if (row < L_) {
      const float* xr = X + ((size_t)n * L_ + row) * A_;
      if (c0 < A_)     v0 = xr[c0];
      if (c0 + 1 < A_) v1 = xr[c0 + 1];
    }
    unsigned int o = (unsigned int)f2bf(v0) | ((unsigned int)f2bf(v1) << 16);
    Xp32[(size_t)rl * 12 + w] = o;
  }
}

// Conv as one GEMM: M=u (A=R slots), N=l (B=packed-X window), K=480 (15 steps).
// R19 = R18 persistent-R + DOUBLE-ACCUMULATOR STORE PIPELINING: tile t's
// K-loop computes into acc(cur) while tile t-1's 32 Z-stores are interleaved
// between K-steps (4 stores after each of steps 1..8) -- the 128 KB/CU store
// burst becomes a stream spread over the 9.3K-cyc K-loop (wall -> max, not
// sum). X for tile t+1 is T14 reg-staged: 7 global_load_dwordx4 issued at
// step 0 (OLDEST, before any stores), vmcnt(32) at loop end retires exactly
// them, ds_write to the private buffer; tile heads have NO waits. Interleaved
// stores (tiles 0..2) are provably in-bounds (l <= 767 < 1005): guard-free.
// 1 wave/SIMD -> full 512-VGPR file; ~380 live VGPR. Zero barriers after
// prologue; lds_r (120 KB) read-only. 4 waves (2u x 2l), wave 64u x 128l.
__global__ __launch_bounds__(256, 1) void conv_kernel(
    const unsigned short* __restrict__ Xp,
    const unsigned short* __restrict__ Rt,
    float* __restrict__ out) {
  __shared__ __align__(16) unsigned short lds_r[NSTEP * 4096];     // 120 KB
  __shared__ __align__(16) unsigned short lds_xp[4][XWCH * 512];   // 28 KB

  const int n  = blockIdx.z;
  const int u0 = blockIdx.x * 128;
  const int wid  = threadIdx.x >> 6;
  const int lane = threadIdx.x & 63;
  const int wl = wid >> 1;             // wave l position (0..1), 128 l each
  const int wu = wid & 1;              // wave u position (0..1), 64 u each

  // wave's private X source: rows t*256 + wl*128 .. +149 (halo 19 incl.)
  const char* xsrc = (const char*)Xp +
      ((size_t)n * XROWS + wl * 128) * (XPR * 2);
  const char* rsrc = (const char*)Rt + (size_t)u0 * 64;   // block's u-half
  char* xdst = (char*)&lds_xp[wid][0];

  // ---- prologue: ALL of R (30 chunks/wave, shared) + private X tile 0
  for (int c = wid; c < NSTEP * 8; c += 4)
    gload_lds16(rsrc + (size_t)(c >> 3) * (U_ * 64) + (c & 7) * 1024 + lane * 16,
                (char*)lds_r + c * 1024);
#pragma unroll
  for (int c = 0; c < XWCH; ++c)
    gload_lds16(xsrc + c * 1024 + lane * 16, xdst + c * 1024);
  asm volatile("s_waitcnt vmcnt(0)" ::: "memory");
  __builtin_amdgcn_s_barrier();        // the ONLY barrier: lds_r visibility

  const int fl = lane & 15;            // frag row (A: u) / col (B: l)
  const int fj = lane >> 4;            // k sub-chunk (8 shorts each)
  const int rfo = (wu * 64 + fl) * 32 + (fj << 3);
  const unsigned short* xb =
      (const unsigned short*)xdst + fl * XPR + (fj << 3);
  const int ug = fj << 2;

  float* Z = out + SZ_S + SZ_R;
  float pmax[4][4];                    // [ut][reg], carried across all tiles
#pragma unroll
  for (int ut = 0; ut < 4; ++ut)
#pragma unroll
    for (int r = 0; r < 4; ++r) pmax[ut][r] = -INFINITY;

  f32x4 accA[4][8], accB[4][8];        // double accumulators (256 VGPR)
  uint4v xr[XWCH];                     // X reg-stage for next tile (28 VGPR)

#define ZERO(ACC)                                                            \
  {                                                                          \
    _Pragma("unroll")                                                        \
    for (int ut = 0; ut < 4; ++ut)                                           \
      _Pragma("unroll")                                                      \
      for (int lt = 0; lt < 8; ++lt)                                         \
        (ACC)[ut][lt] = (f32x4){0.f, 0.f, 0.f, 0.f};                         \
  }

#define KSTEP(K, ACC)                                                        \
  {                                                                          \
    short8 xfr[8], rfr[4];                                                   \
    const unsigned short* rb = lds_r + (K) * 4096 + rfo;                     \
    _Pragma("unroll")                                                        \
    for (int lt = 0; lt < 8; ++lt)                                           \
      xfr[lt] = *(const short8*)(xb + lt * (16 * XPR) + (K) * 32);           \
    _Pragma("unroll")                                                        \
    for (int ut = 0; ut < 4; ++ut)                                           \
      rfr[ut] = *(const short8*)(rb + ut * (16 * 32));                       \
    _Pragma("unroll")                                                        \
    for (int ut = 0; ut < 4; ++ut)                                           \
      _Pragma("unroll")                                                      \
      for (int lt = 0; lt < 8; ++lt)                                         \
        (ACC)[ut][lt] = __builtin_amdgcn_mfma_f32_16x16x32_bf16(             \
            rfr[ut], xfr[lt], (ACC)[ut][lt], 0, 0, 0);                       \
  }

  // store lt-group LT of tile TT from ACC (tiles 0..2: always in-bounds)
#define STORE4(ACC, TT, LT)                                                  \
  {                                                                          \
    const int l = (TT) * 256 + wl * 128 + (LT) * 16 + fl;                    \
    float* zrow = Z + ((size_t)n * LOUT + l) * U_ + u0 + wu * 64 + ug;       \
    _Pragma("unroll")                                                        \
    for (int ut = 0; ut < 4; ++ut) {                                         \
      f32x4 v = (ACC)[ut][LT];                                               \
      *(f32x4*)(zrow + ut * 16) = v;                                         \
      _Pragma("unroll")                                                      \
      for (int r = 0; r < 4; ++r) pmax[ut][r] = fmaxf(pmax[ut][r], v[r]);    \
    }                                                                        \
  }

#define XLOADS(T1)                                                           \
  {                                                                          \
    const char* xs = xsrc + (size_t)(T1) * (256 * XPR * 2);                  \
    _Pragma("unroll")                                                        \
    for (int c = 0; c < XWCH; ++c)                                           \
      xr[c] = *(const uint4v*)(xs + c * 1024 + lane * 16);                   \
  }

#define XWRITE()                                                             \
  {                                                                          \
    _Pragma("unroll")                                                        \
    for (int c = 0; c < XWCH; ++c)                                           \
      *(uint4v*)(xdst + c * 1024 + lane * 16) = xr[c];                       \
  }

  // ---- tile 0: compute accA; reg-load X1 (issued before any stores)
  ZERO(accA)
  XLOADS(1)
#pragma unroll
  for (int k = 0; k < NSTEP; ++k) KSTEP(k, accA)
  asm volatile("s_waitcnt vmcnt(0)" ::: "memory");   // xr ready (only loads)
  XWRITE()

  // ---- tile 1: compute accB; interleave stores of tile 0; reg-load X2
  ZERO(accB)
  XLOADS(2)
#pragma unroll
  for (int k = 0; k < NSTEP; ++k) {
    KSTEP(k, accB)
    if (k >= 1 && k <= 8) STORE4(accA, 0, k - 1)
  }
  asm volatile("s_waitcnt vmcnt(32)" ::: "memory");  // retire 7 oldest = xloads
  XWRITE()

  // ---- tile 2: compute accA; interleave stores of tile 1; reg-load X3
  ZERO(accA)
  XLOADS(3)
#pragma unroll
  for (int k = 0; k < NSTEP; ++k) {
    KSTEP(k, accA)
    if (k >= 1 && k <= 8) STORE4(accB, 1, k - 1)
  }
  asm volatile("s_waitcnt vmcnt(32)" ::: "memory");
  XWRITE()

  // ---- tile 3: compute accB; interleave stores of tile 2
  ZERO(accB)
#pragma unroll
  for (int k = 0; k < NSTEP; ++k) {
    KSTEP(k, accB)
    if (k >= 1 && k <= 8) STORE4(accA, 2, k - 1)
  }

  // ---- tail: store tile 3 (guarded: rows 768..1023 vs LOUT=1005)
#pragma unroll
  for (int lt = 0; lt < 8; ++lt) {
    const int l = 768 + wl * 128 + lt * 16 + fl;
    if (l < LOUT) {
      float* zrow = Z + ((size_t)n * LOUT + l) * U_ + u0 + wu * 64 + ug;
#pragma unroll
      for (int ut = 0; ut < 4; ++ut) {
        f32x4 v = accB[ut][lt];
        *(f32x4*)(zrow + ut * 16) = v;
#pragma unroll
        for (int r = 0; r < 4; ++r) pmax[ut][r] = fmaxf(pmax[ut][r], v[r]);
      }
    }
  }

#undef ZERO
#undef KSTEP
#undef STORE4
#undef XLOADS
#undef XWRITE

  // ---- S epilogue: reduce over the frag's 16 cols (fl), atomics once.
#pragma unroll
  for (int off = 1; off < 16; off <<= 1)
#pragma unroll
    for (int ut = 0; ut < 4; ++ut)
#pragma unroll
      for (int r = 0; r < 4; ++r)
        pmax[ut][r] = fmaxf(pmax[ut][r], __shfl_xor(pmax[ut][r], off));

  if (fl == 0) {                       // lanes fj*16
    const int tn = n / F_;
    float* Sp = out + (size_t)tn * U_ + u0 + wu * 64 + ug;
#pragma unroll
    for (int ut = 0; ut < 4; ++ut)
#pragma unroll
      for (int r = 0; r < 4; ++r)
        atomicMaxF(Sp + ut * 16 + r, pmax[ut][r]);
  }
}

extern "C" void kernel_launch(void* const* d_in, const int* in_sizes, int n_in,
                              void* d_out, int out_size, void* d_ws, size_t ws_size,
                              hipStream_t stream) {
  const float* X       = (const float*)d_in[0];
  const float* P_logit = (const float*)d_in[1];
  const float* Q       = (const float*)d_in[2];
  float* out = (float*)d_out;

  unsigned short* Rt = (unsigned short*)d_ws;            // 240 KB
  unsigned short* Xp = (unsigned short*)((char*)d_ws + 262144);
  // Xp: NIMG*XROWS*24 shorts (~18.6 MB). All staged rows <= 1045 < 1056:
  // fully in-bounds; no over-read.

  int xthreads = NIMG * XROWS * 12;
  hipLaunchKernelGGL(xprep_kernel, dim3((xthreads + 255) / 256), dim3(256),
                     0, stream, X, P_logit, Q, out, Rt, (unsigned int*)Xp);
  dim3 grid(2, 1, NIMG);   // u-tiles, -, images (4 l-tiles looped in-kernel)
  hipLaunchKernelGGL(conv_kernel, grid, dim3(256), 0, stream, Xp, Rt, out);
}